// Round 2
// 472.592 us; speedup vs baseline: 1.2726x; 1.2726x over previous
//
#include <hip/hip_runtime.h>

typedef _Float16 half8_t __attribute__((ext_vector_type(8)));
typedef _Float16 half4_t __attribute__((ext_vector_type(4)));
typedef float floatx4 __attribute__((ext_vector_type(4)));

// async global->LDS, 16B per lane. lds ptr wave-uniform; HW writes lane L at
// ldsbase + L*16.
__device__ inline void gload16(const void* g, void* l) {
  __builtin_amdgcn_global_load_lds(
      (const __attribute__((address_space(1))) unsigned int*)g,
      (__attribute__((address_space(3))) unsigned int*)l, 16, 0, 0);
}

// ======================= 256x256 8-phase BT GEMM =========================
// C[m,n] = sum_h A[m,h]*B[n,h] (+bias). fp16 operands, K-contiguous rows.
// K fixed = 1024 (16 K-tiles of BK=64).
// 512 threads = 8 waves in 2(row) x 4(col); per phase all 8 waves compute one
// 128x128 C-quadrant (wave slice 64x32).
// LDS (128 KiB): per operand per parity, 256 rows x 64 k fp16 stored
// chunk-transposed: 16B chunk (kb,m) holds row m, k in [kb*8,kb*8+8) at
// offset (kb*256+m)*16. Conflict-free for both gload_lds (linear dest) and
// ds_read_b128 frags (lanes 0-15 -> consecutive chunks).
// Pipeline per K-tile t (parity p=t&1, q=p^1), quadrants (0,0),(0,1),(1,1),(1,0):
//   P1: ds-read A0,B0 frags; stage t+1.B0 -> q
//   P2: ds-read B1;          stage t+2.A0 -> p   (A0[p] dead after P1)
//   P3: ds-read A1;          stage t+2.B1 -> p   (B1[p] dead after P2)
//   P4: ds-read B0 again;    stage t+2.A1 -> p   (A1[p] dead after P3)
//       then s_waitcnt vmcnt(6): forces everything through t+1.B0 (issued
//       P1(t)) while the 3 newest half-tiles (6 loads/wave) stay in flight.
// Each phase: {ds-reads; stage; [vmcnt]; s_barrier; lgkmcnt(0); setprio(1);
//              16 MFMA; setprio(0); s_barrier}.  vmcnt never drains to 0.
constexpr int NT = 16;  // K / 64

template <int MH>
__device__ inline void lda_frags(const char* sA, int wr, int quad, int mrow,
                                 half8_t af[4][2]) {
#pragma unroll
  for (int mf = 0; mf < 4; ++mf)
#pragma unroll
    for (int kk = 0; kk < 2; ++kk)
      af[mf][kk] = *(const half8_t*)(
          sA + (size_t)(((kk * 4 + quad) * 256 + MH * 128 + wr * 64 +
                         mf * 16 + mrow) << 4));
}

template <int NH>
__device__ inline void ldb_frags(const char* sB, int wc, int quad, int mrow,
                                 half8_t bf[2][2]) {
#pragma unroll
  for (int nf = 0; nf < 2; ++nf)
#pragma unroll
    for (int kk = 0; kk < 2; ++kk)
      bf[nf][kk] = *(const half8_t*)(
          sB + (size_t)(((kk * 4 + quad) * 256 + NH * 128 + wc * 32 +
                         nf * 16 + mrow) << 4));
}

template <int MH, int NH>
__device__ inline void mfma_quad(const half8_t af[4][2], const half8_t bf[2][2],
                                 floatx4 acc[8][4]) {
  __builtin_amdgcn_s_setprio(1);
#pragma unroll
  for (int mf = 0; mf < 4; ++mf)
#pragma unroll
    for (int nf = 0; nf < 2; ++nf)
#pragma unroll
      for (int kk = 0; kk < 2; ++kk)
        acc[MH * 4 + mf][NH * 2 + nf] = __builtin_amdgcn_mfma_f32_16x16x32_f16(
            af[mf][kk], bf[nf][kk], acc[MH * 4 + mf][NH * 2 + nf], 0, 0, 0);
  __builtin_amdgcn_s_setprio(0);
}

// stage half h (rows [h*128, h*128+128)) of K-tile u of operand X into the
// parity-resolved operand base. X must ALREADY include the block tile offset
// (m0*lda / n0*ldb). wave wid covers kb=wid, 2 issues (mseg 0/1).
__device__ inline void stage_half(const _Float16* __restrict__ X, int ldx,
                                  int u, char* opbase, int h, int wid,
                                  int lane) {
#pragma unroll
  for (int i = 0; i < 2; ++i) {
    gload16(X + (long)(h * 128 + i * 64 + lane) * ldx + u * 64 + wid * 8,
            opbase + (size_t)((wid * 256 + h * 128 + i * 64) << 4));
  }
}

template <typename OT, int BIAS, int GX, int GY>
__global__ __launch_bounds__(512, 2) void gemm256(
    const _Float16* __restrict__ A, long As, int lda,
    const _Float16* __restrict__ B, long Bs, int ldb,
    OT* __restrict__ C, long Cs, int ldc,
    const float* __restrict__ bias, int biasStride) {
  __shared__ char smem[131072];  // A: p*32768, B: 65536 + p*32768

  // XCD chunk swizzle: consecutive swizzled ids land on one XCD (id%8=XCD
  // under RR dispatch). grids here are 256/512, always %8==0.
  const int id = blockIdx.x;
  const int chunk = gridDim.x >> 3;
  const int nid = (id & 7) * chunk + (id >> 3);
  const int bx = nid % GX;
  const int by = (nid / GX) % GY;
  const int bz = nid / (GX * GY);

  const int tid = threadIdx.x;
  const int lane = tid & 63;
  const int wid = tid >> 6;        // 0..7
  const int wr = wid >> 2;         // 0..1  (64-row slice within quadrant)
  const int wc = wid & 3;          // 0..3  (32-col slice within quadrant)
  const int quad = lane >> 4;
  const int mrow = lane & 15;
  const long m0 = (long)by * 256;
  const long n0 = (long)bx * 256;
  // tile-offset staging bases (fix: previous round omitted m0/n0 here)
  const _Float16* Ab = A + (long)bz * As + m0 * (long)lda;
  const _Float16* Bb = B + (long)bz * Bs + n0 * (long)ldb;
  C += (long)bz * Cs;

  floatx4 acc[8][4] = {};
  half8_t af[4][2], bf[2][2];

  // ---- prologue: issue t0.{A0,B1,A1,B0}, t1.{A0,B1,A1}; force t0 resident.
  {
    char* sA0 = smem;
    char* sB0 = smem + 65536;
    char* sA1 = smem + 32768;
    char* sB1 = smem + 65536 + 32768;
    stage_half(Ab, lda, 0, sA0, 0, wid, lane);
    stage_half(Bb, ldb, 0, sB0, 1, wid, lane);
    stage_half(Ab, lda, 0, sA0, 1, wid, lane);
    stage_half(Bb, ldb, 0, sB0, 0, wid, lane);
    stage_half(Ab, lda, 1, sA1, 0, wid, lane);
    stage_half(Bb, ldb, 1, sB1, 1, wid, lane);
    stage_half(Ab, lda, 1, sA1, 1, wid, lane);
    asm volatile("s_waitcnt vmcnt(6)" ::: "memory");
    __builtin_amdgcn_s_barrier();
  }

  for (int t = 0; t < NT; ++t) {
    const int p = t & 1, q = p ^ 1;
    char* sAp = smem + p * 32768;
    char* sBp = smem + 65536 + p * 32768;
    char* sBq = smem + 65536 + q * 32768;
    // clamped tail re-stages keep issue counts uniform (vmcnt math intact);
    // duplicate writes hit dead-or-identical slots only.
    const int u1 = (t + 1 < NT) ? t + 1 : NT - 1;
    const int u2 = (t + 2 < NT) ? t + 2 : NT - 1;

    // ---- P1: quadrant (0,0)
    lda_frags<0>(sAp, wr, quad, mrow, af);
    ldb_frags<0>(sBp, wc, quad, mrow, bf);
    stage_half(Bb, ldb, u1, sBq, 0, wid, lane);  // t+1.B0 -> q
    __builtin_amdgcn_s_barrier();
    asm volatile("s_waitcnt lgkmcnt(0)" ::: "memory");
    mfma_quad<0, 0>(af, bf, acc);
    __builtin_amdgcn_s_barrier();

    // ---- P2: quadrant (0,1) (reuse A0 regs)
    ldb_frags<1>(sBp, wc, quad, mrow, bf);
    stage_half(Ab, lda, u2, sAp, 0, wid, lane);  // t+2.A0 -> p
    __builtin_amdgcn_s_barrier();
    asm volatile("s_waitcnt lgkmcnt(0)" ::: "memory");
    mfma_quad<0, 1>(af, bf, acc);
    __builtin_amdgcn_s_barrier();

    // ---- P3: quadrant (1,1) (reuse B1 regs)
    lda_frags<1>(sAp, wr, quad, mrow, af);
    stage_half(Bb, ldb, u2, sBp, 1, wid, lane);  // t+2.B1 -> p
    __builtin_amdgcn_s_barrier();
    asm volatile("s_waitcnt lgkmcnt(0)" ::: "memory");
    mfma_quad<1, 1>(af, bf, acc);
    __builtin_amdgcn_s_barrier();

    // ---- P4: quadrant (1,0) (reuse A1 regs, re-read B0)
    ldb_frags<0>(sBp, wc, quad, mrow, bf);
    stage_half(Ab, lda, u2, sAp, 1, wid, lane);  // t+2.A1 -> p
    asm volatile("s_waitcnt vmcnt(6)" ::: "memory");
    __builtin_amdgcn_s_barrier();
    asm volatile("s_waitcnt lgkmcnt(0)" ::: "memory");
    mfma_quad<1, 0>(af, bf, acc);
    __builtin_amdgcn_s_barrier();
  }

  asm volatile("s_waitcnt vmcnt(0)" ::: "memory");

  // epilogue: C/D layout col = lane&15, row = quad*4 + r (per 16x16 frag)
#pragma unroll
  for (int mh = 0; mh < 2; ++mh)
#pragma unroll
    for (int mf = 0; mf < 4; ++mf) {
      const int rbase = mh * 128 + wr * 64 + mf * 16 + quad * 4;
#pragma unroll
      for (int nh = 0; nh < 2; ++nh)
#pragma unroll
        for (int nf = 0; nf < 2; ++nf) {
          const int cc = (int)n0 + nh * 128 + wc * 32 + nf * 16 + mrow;
#pragma unroll
          for (int r = 0; r < 4; ++r) {
            const long row = m0 + rbase + r;
            float v = acc[mh * 4 + mf][nh * 2 + nf][r];
            if constexpr (BIAS == 1) v += bias[bz * biasStride + cc];
            if constexpr (BIAS == 2) v += bias[(int)row];
            C[row * (long)ldc + cc] = (OT)v;
          }
        }
    }
}

// ===================== auxiliary kernels (unchanged) =====================

// fp32 -> fp16, one float4 chunk per thread, 3 tensors of 16M floats each.
__global__ __launch_bounds__(256) void convert_x(const float* __restrict__ x0,
                                                 const float* __restrict__ x1,
                                                 const float* __restrict__ x2,
                                                 _Float16* __restrict__ out) {
  int i = blockIdx.x * 256 + threadIdx.x;  // 12582912 chunks total
  int t = i >> 22;                         // 4194304 chunks per tensor
  int j = i & 4194303;
  const float* src = (t == 0) ? x0 : (t == 1) ? x1 : x2;
  floatx4 v = ((const floatx4*)src)[j];
  half4_t h = {(_Float16)v[0], (_Float16)v[1], (_Float16)v[2], (_Float16)v[3]};
  ((half4_t*)out)[i] = h;
}

__global__ __launch_bounds__(256) void convert_w(const float* __restrict__ Wq,
                                                 const float* __restrict__ Wk,
                                                 const float* __restrict__ Wv,
                                                 _Float16* __restrict__ out) {
  int i = blockIdx.x * 256 + threadIdx.x;  // 786432 chunks total
  int t = i >> 18;                         // 262144 chunks per tensor
  int j = i & 262143;
  const float* src = (t == 0) ? Wq : (t == 1) ? Wk : Wv;
  floatx4 v = ((const floatx4*)src)[j];
  half4_t h = {(_Float16)v[0], (_Float16)v[1], (_Float16)v[2], (_Float16)v[3]};
  ((half4_t*)out)[i] = h;
}

// pack bq|bk|bv into one contiguous [3*1024] float array
__global__ __launch_bounds__(256) void pack_bias(const float* __restrict__ bq,
                                                 const float* __restrict__ bk,
                                                 const float* __restrict__ bv,
                                                 float* __restrict__ out) {
  int b = blockIdx.x;
  const float* src = (b == 0) ? bq : (b == 1) ? bk : bv;
  ((floatx4*)out)[b * 256 + threadIdx.x] =
      ((const floatx4*)src)[threadIdx.x];
}

// Row softmax over 1024 fp16 scores, fp32 math, fp16 result in place.
__global__ __launch_bounds__(256) void softmax_rows_h(_Float16* __restrict__ S) {
  long row = blockIdx.x;
  _Float16* Sr = S + row * 1024;
  int tid = threadIdx.x, lane = tid & 63, wid = tid >> 6;
  half4_t x = ((const half4_t*)Sr)[tid];
  float x0 = x[0], x1 = x[1], x2 = x[2], x3 = x[3];
  float mx = fmaxf(fmaxf(x0, x1), fmaxf(x2, x3));
#pragma unroll
  for (int off = 32; off > 0; off >>= 1) mx = fmaxf(mx, __shfl_xor(mx, off));
  __shared__ float redm[4];
  if (lane == 0) redm[wid] = mx;
  __syncthreads();
  mx = fmaxf(fmaxf(redm[0], redm[1]), fmaxf(redm[2], redm[3]));
  float e0 = __expf(x0 - mx), e1 = __expf(x1 - mx);
  float e2 = __expf(x2 - mx), e3 = __expf(x3 - mx);
  float s = e0 + e1 + e2 + e3;
#pragma unroll
  for (int off = 32; off > 0; off >>= 1) s += __shfl_xor(s, off);
  __shared__ float reds[4];
  if (lane == 0) reds[wid] = s;
  __syncthreads();
  s = reds[0] + reds[1] + reds[2] + reds[3];
  float inv = 1.0f / s;
  half4_t h = {(_Float16)(e0 * inv), (_Float16)(e1 * inv),
               (_Float16)(e2 * inv), (_Float16)(e3 * inv)};
  ((half4_t*)Sr)[tid] = h;
}

extern "C" void kernel_launch(void* const* d_in, const int* in_sizes, int n_in,
                              void* d_out, int out_size, void* d_ws,
                              size_t ws_size, hipStream_t stream) {
  (void)in_sizes; (void)n_in; (void)out_size; (void)ws_size;
  const float* meme  = (const float*)d_in[0];
  const float* text  = (const float*)d_in[1];
  const float* emoji = (const float*)d_in[2];
  const float* Wq = (const float*)d_in[3];
  const float* bq = (const float*)d_in[4];
  const float* Wk = (const float*)d_in[5];
  const float* bk = (const float*)d_in[6];
  const float* Wv = (const float*)d_in[7];
  const float* bv = (const float*)d_in[8];

  const long MB = 1024 * 1024;
  char* ws = (char*)d_ws;
  // [0,6) MB:    hWq/hWk/hWv fp16 (contiguous, stride 1M halves)
  // [6, 6.0125): packed bias 3*1024 fp32 (12 KB) -> round region to 7 MB
  // [7,39) MB:   meme_h  -> dead after QK GEMM -> reused as S (fp16, 32MB)
  // [39,71) MB:  text_h  -> dead after QK GEMM -> reused as Vt (fp16, 32MB)
  // [71,103) MB: emoji_h -> dead after Vt GEMM
  // [103,135):   Qh fp16   [135,167): Kh fp16   => total 167 MB
  _Float16* hWq = (_Float16*)ws;
  float* pbias  = (float*)(ws + 6 * MB);
  _Float16* mh  = (_Float16*)(ws + 7 * MB);
  _Float16* th  = (_Float16*)(ws + 39 * MB);
  _Float16* eh  = (_Float16*)(ws + 71 * MB);
  _Float16* Qh  = (_Float16*)(ws + 103 * MB);
  _Float16* Kh  = (_Float16*)(ws + 135 * MB);
  _Float16* S   = mh;  // aliases meme_h (dead by then)
  _Float16* Vt  = th;  // aliases text_h (dead by then)
  _Float16* hWv = hWq + 2 * MB;

  dim3 blk(256), blk5(512);
  convert_w<<<3072, blk, 0, stream>>>(Wq, Wk, Wv, hWq);
  pack_bias<<<3, blk, 0, stream>>>(bq, bk, bv, pbias);
  convert_x<<<49152, blk, 0, stream>>>(meme, text, emoji, mh);

  // Q,K projections batched (z=2): M=16384 (GY=64), N=1024 (GX=4).
  gemm256<_Float16, 1, 4, 64><<<dim3(512), blk5, 0, stream>>>(
      mh, 16777216, 1024, hWq, 1048576, 1024, Qh, 16777216, 1024, pbias, 1024);
  // Vt[a, b*L+l] = sum_h Wv[a,h]*emoji[b,l,h] + bv[a]  (V transposed)
  // M=1024 (GY=4), N=16384 (GX=64).
  gemm256<_Float16, 2, 64, 4><<<dim3(256), blk5, 0, stream>>>(
      hWv, 0, 1024, eh, 0, 1024, Vt, 0, 16384, pbias + 2048, 0);
  // S[b] = Q[b] @ K[b]^T -> fp16. per-batch 1024x1024, z=16.
  gemm256<_Float16, 0, 4, 4><<<dim3(256), blk5, 0, stream>>>(
      Qh, 1048576, 1024, Kh, 1048576, 1024, S, 1048576, 1024, nullptr, 0);
  // softmax rows, fp16 in place
  softmax_rows_h<<<16384, blk, 0, stream>>>(S);
  // O[b] = P[b] @ V[b] via Vt: C[q,a] = sum_k P[q,k] * Vt[a, b*1024+k]
  gemm256<float, 0, 4, 4><<<dim3(256), blk5, 0, stream>>>(
      S, 1048576, 1024, Vt, 1024, 16384, (float*)d_out, 1048576, 1024,
      nullptr, 0);
}